// Round 1
// baseline (2096.826 us; speedup 1.0000x reference)
//
#include <hip/hip_runtime.h>
#include <hip/hip_bf16.h>
#include <cstddef>

// ---------------------------------------------------------------------------
// CascadeRCNN head: ROIAlignV2 (4 FPN levels) -> fc1(relu) -> fc2(relu) -> pred
// fp32 throughout (round 0: correctness-first).
// ---------------------------------------------------------------------------

#define NROIS 1024
#define C_CH  256
#define OUTP  7
#define PSAMP 14            // OUT * RATIO
#define DFEAT (C_CH * OUTP * OUTP)   // 12544
#define HID   1024
#define NCLS  20            // 5 * NUM_CLASSES * NHEADS

// ------------------------------- ROI ALIGN ---------------------------------
// grid = NROIS blocks, block = 256 threads (one per channel).
__global__ __launch_bounds__(256) void roi_pool_kernel(
    const float* __restrict__ fm0, const float* __restrict__ fm1,
    const float* __restrict__ fm2, const float* __restrict__ fm3,
    const float* __restrict__ rois, float* __restrict__ pooled)
{
    const int roi = blockIdx.x;
    const int c   = threadIdx.x;

    __shared__ float s_box[5];
    __shared__ int   s_ix0[PSAMP], s_ix1[PSAMP], s_iy0[PSAMP], s_iy1[PSAMP];
    __shared__ float s_wx0[PSAMP], s_wx1[PSAMP], s_wy0[PSAMP], s_wy1[PSAMP];

    if (c < 5) s_box[c] = rois[(size_t)roi * 5 + c];
    __syncthreads();

    const int   b   = (int)s_box[0];
    const float bx1 = s_box[1], by1 = s_box[2], bx2 = s_box[3], by2 = s_box[4];

    // level selection (matches reference: k = floor(4 + log2(sqrt(max(w*h,1e-6))/224)))
    const float w  = bx2 - bx1;
    const float h  = by2 - by1;
    float kf = floorf(4.0f + log2f(sqrtf(fmaxf(w * h, 1e-6f)) / 224.0f));
    kf = fminf(fmaxf(kf, 2.0f), 5.0f);
    const int lvl    = (int)kf - 2;
    const int stride = 4 << lvl;
    const int H  = 768  / stride;
    const int Wd = 1280 / stride;

    const float* fm = (lvl == 0) ? fm0 : (lvl == 1) ? fm1 : (lvl == 2) ? fm2 : fm3;

    // precompute bilinear axis data into LDS
    if (c < PSAMP) {
        const float x1s = bx1 / (float)stride - 0.5f;
        const float x2s = bx2 / (float)stride - 0.5f;
        const float coord = x1s + (x2s - x1s) * (((float)c + 0.5f) / (float)PSAMP);
        const float valid = (coord > -1.0f && coord < (float)Wd) ? 1.0f : 0.0f;
        const float cc = fminf(fmaxf(coord, 0.0f), (float)(Wd - 1));
        const int i0 = (int)floorf(cc);
        const int i1 = min(i0 + 1, Wd - 1);
        const float fr = cc - (float)i0;
        s_ix0[c] = i0; s_ix1[c] = i1;
        s_wx0[c] = (1.0f - fr) * valid; s_wx1[c] = fr * valid;
    } else if (c >= 16 && c < 16 + PSAMP) {
        const int j = c - 16;
        const float y1s = by1 / (float)stride - 0.5f;
        const float y2s = by2 / (float)stride - 0.5f;
        const float coord = y1s + (y2s - y1s) * (((float)j + 0.5f) / (float)PSAMP);
        const float valid = (coord > -1.0f && coord < (float)H) ? 1.0f : 0.0f;
        const float cc = fminf(fmaxf(coord, 0.0f), (float)(H - 1));
        const int i0 = (int)floorf(cc);
        const int i1 = min(i0 + 1, H - 1);
        const float fr = cc - (float)i0;
        s_iy0[j] = i0; s_iy1[j] = i1;
        s_wy0[j] = (1.0f - fr) * valid; s_wy1[j] = fr * valid;
    }
    __syncthreads();

    const float* fb = fm + ((size_t)b * C_CH + c) * (size_t)(H * Wd);
    float* outp = pooled + (size_t)roi * DFEAT + (size_t)c * (OUTP * OUTP);

    #pragma unroll
    for (int oy = 0; oy < OUTP; ++oy) {
        #pragma unroll
        for (int ox = 0; ox < OUTP; ++ox) {
            float acc = 0.0f;
            #pragma unroll
            for (int sy = 0; sy < 2; ++sy) {
                const int jy = oy * 2 + sy;
                const int y0 = s_iy0[jy], y1 = s_iy1[jy];
                const float a0 = s_wy0[jy], a1 = s_wy1[jy];
                const float* r0 = fb + (size_t)y0 * Wd;
                const float* r1 = fb + (size_t)y1 * Wd;
                #pragma unroll
                for (int sx = 0; sx < 2; ++sx) {
                    const int jx = ox * 2 + sx;
                    const int x0 = s_ix0[jx], x1i = s_ix1[jx];
                    const float b0 = s_wx0[jx], b1 = s_wx1[jx];
                    acc += a0 * (b0 * r0[x0] + b1 * r0[x1i])
                         + a1 * (b0 * r1[x0] + b1 * r1[x1i]);
                }
            }
            outp[oy * OUTP + ox] = acc * 0.25f;
        }
    }
}

// ------------------------------- GEMM (fp32) -------------------------------
// C[M,N] = relu?(A[M,K] @ W[N,K]^T + bias[N])
// 64x64 tile, K-tile 32, 256 threads, 4x4 per thread. k-major LDS, stride 68
// (16B-aligned fragment rows -> ds_read_b128).
#define TM 64
#define TN 64
#define TK 32
#define LDP 68

__global__ __launch_bounds__(256) void gemm_bias_relu(
    const float* __restrict__ A, const float* __restrict__ Wm,
    const float* __restrict__ bias, float* __restrict__ C,
    int K, int N, int relu)
{
    __shared__ __align__(16) float As[TK][LDP];
    __shared__ __align__(16) float Bs[TK][LDP];

    const int t  = threadIdx.x;
    const int tx = t & 15;       // -> n
    const int ty = t >> 4;       // -> m
    const int bm = blockIdx.y * TM;
    const int bn = blockIdx.x * TN;

    float acc[4][4];
    #pragma unroll
    for (int i = 0; i < 4; ++i)
        #pragma unroll
        for (int j = 0; j < 4; ++j) acc[i][j] = 0.0f;

    for (int k0 = 0; k0 < K; k0 += TK) {
        // stage A and W tiles: 64 rows x 32 k each = 512 float4 per operand
        #pragma unroll
        for (int q = 0; q < 2; ++q) {
            const int idx = t + q * 256;
            const int row = idx >> 3;          // 0..63
            const int kc  = (idx & 7) << 2;    // 0,4,...,28
            const float4 va = *(const float4*)(A  + (size_t)(bm + row) * K + (k0 + kc));
            As[kc + 0][row] = va.x; As[kc + 1][row] = va.y;
            As[kc + 2][row] = va.z; As[kc + 3][row] = va.w;
            const float4 vw = *(const float4*)(Wm + (size_t)(bn + row) * K + (k0 + kc));
            Bs[kc + 0][row] = vw.x; Bs[kc + 1][row] = vw.y;
            Bs[kc + 2][row] = vw.z; Bs[kc + 3][row] = vw.w;
        }
        __syncthreads();

        #pragma unroll 8
        for (int k = 0; k < TK; ++k) {
            const float4 a4 = *(const float4*)&As[k][ty * 4];
            const float4 b4 = *(const float4*)&Bs[k][tx * 4];
            const float a[4] = {a4.x, a4.y, a4.z, a4.w};
            const float b[4] = {b4.x, b4.y, b4.z, b4.w};
            #pragma unroll
            for (int i = 0; i < 4; ++i)
                #pragma unroll
                for (int j = 0; j < 4; ++j)
                    acc[i][j] = fmaf(a[i], b[j], acc[i][j]);
        }
        __syncthreads();
    }

    const int n = bn + tx * 4;
    #pragma unroll
    for (int i = 0; i < 4; ++i) {
        const int m = bm + ty * 4 + i;
        float4 v;
        v.x = acc[i][0] + bias[n + 0];
        v.y = acc[i][1] + bias[n + 1];
        v.z = acc[i][2] + bias[n + 2];
        v.w = acc[i][3] + bias[n + 3];
        if (relu) {
            v.x = fmaxf(v.x, 0.0f); v.y = fmaxf(v.y, 0.0f);
            v.z = fmaxf(v.z, 0.0f); v.w = fmaxf(v.w, 0.0f);
        }
        *(float4*)(C + (size_t)m * N + n) = v;
    }
}

// ------------------------------ PREDICTOR ----------------------------------
// out[1024,20] = A[1024,1024] @ p_w[20,1024]^T + p_b
// one block per roi row; 8 K-slices x 32 lanes (cols 0..19 active).
__global__ __launch_bounds__(256) void pred_kernel(
    const float* __restrict__ A, const float* __restrict__ Wm,
    const float* __restrict__ bias, float* __restrict__ out)
{
    const int i = blockIdx.x;
    const int t = threadIdx.x;
    const int j = t & 31;   // col
    const int s = t >> 5;   // K slice 0..7

    __shared__ float red[8][32];

    float acc = 0.0f;
    if (j < NCLS) {
        const float4* a4 = (const float4*)(A  + (size_t)i * HID + s * 128);
        const float4* w4 = (const float4*)(Wm + (size_t)j * HID + s * 128);
        #pragma unroll 8
        for (int q = 0; q < 32; ++q) {
            const float4 a = a4[q], w = w4[q];
            acc += a.x * w.x + a.y * w.y + a.z * w.z + a.w * w.w;
        }
    }
    red[s][j] = acc;
    __syncthreads();
    if (s == 0 && j < NCLS) {
        float v = bias[j];
        #pragma unroll
        for (int q = 0; q < 8; ++q) v += red[q][j];
        out[(size_t)i * NCLS + j] = v;
    }
}

// ------------------------------- LAUNCH ------------------------------------
extern "C" void kernel_launch(void* const* d_in, const int* in_sizes, int n_in,
                              void* d_out, int out_size, void* d_ws, size_t ws_size,
                              hipStream_t stream) {
    (void)in_sizes; (void)n_in; (void)out_size; (void)ws_size;

    const float* fm0   = (const float*)d_in[0];
    const float* fm1   = (const float*)d_in[1];
    const float* fm2   = (const float*)d_in[2];
    const float* fm3   = (const float*)d_in[3];
    const float* rois  = (const float*)d_in[4];
    const float* fc1_w = (const float*)d_in[5];
    const float* fc1_b = (const float*)d_in[6];
    const float* fc2_w = (const float*)d_in[7];
    const float* fc2_b = (const float*)d_in[8];
    const float* p_w   = (const float*)d_in[9];
    const float* p_b   = (const float*)d_in[10];

    float* pooled = (float*)d_ws;                          // [1024, 12544]
    float* fc1_o  = pooled + (size_t)NROIS * DFEAT;        // [1024, 1024]
    float* fc2_o  = fc1_o  + (size_t)NROIS * HID;          // [1024, 1024]
    float* outp   = (float*)d_out;                         // [1024, 20]

    roi_pool_kernel<<<NROIS, 256, 0, stream>>>(fm0, fm1, fm2, fm3, rois, pooled);

    {
        dim3 grid(HID / TN, NROIS / TM);
        gemm_bias_relu<<<grid, 256, 0, stream>>>(pooled, fc1_w, fc1_b, fc1_o,
                                                 DFEAT, HID, 1);
    }
    {
        dim3 grid(HID / TN, NROIS / TM);
        gemm_bias_relu<<<grid, 256, 0, stream>>>(fc1_o, fc2_w, fc2_b, fc2_o,
                                                 HID, HID, 1);
    }
    pred_kernel<<<NROIS, 256, 0, stream>>>(fc2_o, p_w, p_b, outp);
}

// Round 2
// 548.618 us; speedup vs baseline: 3.8220x; 3.8220x over previous
//
#include <hip/hip_runtime.h>
#include <hip/hip_bf16.h>
#include <cstddef>
#include <cstdint>

// ---------------------------------------------------------------------------
// CascadeRCNN head, round 2:
//   ROIAlign (coalescing-friendly, writes bf16 hi/lo directly)
//   fc1/fc2 via bf16x3-split MFMA GEMM (m97 structure + split-K)
//   reduce kernel fuses split-K sum + bias + relu + next-layer hi/lo split
//   predictor in fp32 (tiny)
// ---------------------------------------------------------------------------

#define NROIS 1024
#define C_CH  256
#define OUTP  7
#define DFEAT (C_CH * OUTP * OUTP)   // 12544
#define HID   1024
#define NCLS  20

// ---------------- bf16 helpers (RTNE) ----------------
__device__ __forceinline__ unsigned short f2bf(float x) {
    union { float f; uint32_t u; } v; v.f = x;
    uint32_t r = v.u + 0x7fffu + ((v.u >> 16) & 1u);
    return (unsigned short)(r >> 16);
}
__device__ __forceinline__ float bf2f(unsigned short h) {
    union { uint32_t u; float f; } v; v.u = ((uint32_t)h) << 16;
    return v.f;
}

// ---------------- async global->LDS (16B/lane) ----------------
__device__ __forceinline__ void g2lds16(const void* g, void* l) {
    __builtin_amdgcn_global_load_lds(
        (const __attribute__((address_space(1))) void*)g,
        (__attribute__((address_space(3))) void*)l,
        16, 0, 0);
}

typedef __attribute__((ext_vector_type(8))) short bf16x8;
typedef __attribute__((ext_vector_type(4))) float f32x4;

// ------------------------------- ROI ALIGN ---------------------------------
// block = one roi (1024 blocks), 256 threads = 4 waves.
// lane -> (jx = lane&15 sample col, grp = lane>>4 sample-row group);
// wave iterates its 64 channels; ky loop covers the 14 sample rows.
// 2x2 bin mean via shfl; writes pooled hi/lo bf16 [roi][c*49+by*7+bx].
__global__ __launch_bounds__(256) void roi_pool_split(
    const float* __restrict__ fm0, const float* __restrict__ fm1,
    const float* __restrict__ fm2, const float* __restrict__ fm3,
    const float* __restrict__ rois,
    unsigned short* __restrict__ ph, unsigned short* __restrict__ pl)
{
    const int roi = blockIdx.x;
    const int t   = threadIdx.x;

    __shared__ float s_box[5];
    __shared__ int   s_ix0[16], s_ix1[16], s_iy0[16], s_iy1[16];
    __shared__ float s_wx0[16], s_wx1[16], s_wy0[16], s_wy1[16];

    if (t < 5) s_box[t] = rois[(size_t)roi * 5 + t];
    __syncthreads();

    const int   b   = (int)s_box[0];
    const float bx1 = s_box[1], by1 = s_box[2], bx2 = s_box[3], by2 = s_box[4];

    const float w = bx2 - bx1, h = by2 - by1;
    float kf = floorf(4.0f + log2f(sqrtf(fmaxf(w * h, 1e-6f)) / 224.0f));
    kf = fminf(fmaxf(kf, 2.0f), 5.0f);
    const int lvl    = (int)kf - 2;
    const int stride = 4 << lvl;
    const int H  = 768  / stride;
    const int Wd = 1280 / stride;
    const float* fm = (lvl == 0) ? fm0 : (lvl == 1) ? fm1 : (lvl == 2) ? fm2 : fm3;

    if (t < 14) {
        const float x1s = bx1 / (float)stride - 0.5f;
        const float x2s = bx2 / (float)stride - 0.5f;
        const float coord = x1s + (x2s - x1s) * (((float)t + 0.5f) / 14.0f);
        const float valid = (coord > -1.0f && coord < (float)Wd) ? 1.0f : 0.0f;
        const float cc = fminf(fmaxf(coord, 0.0f), (float)(Wd - 1));
        const int i0 = (int)floorf(cc);
        s_ix0[t] = i0; s_ix1[t] = min(i0 + 1, Wd - 1);
        const float fr = cc - (float)i0;
        s_wx0[t] = (1.0f - fr) * valid; s_wx1[t] = fr * valid;
    } else if (t >= 16 && t < 30) {
        const int j = t - 16;
        const float y1s = by1 / (float)stride - 0.5f;
        const float y2s = by2 / (float)stride - 0.5f;
        const float coord = y1s + (y2s - y1s) * (((float)j + 0.5f) / 14.0f);
        const float valid = (coord > -1.0f && coord < (float)H) ? 1.0f : 0.0f;
        const float cc = fminf(fmaxf(coord, 0.0f), (float)(H - 1));
        const int i0 = (int)floorf(cc);
        s_iy0[j] = i0; s_iy1[j] = min(i0 + 1, H - 1);
        const float fr = cc - (float)i0;
        s_wy0[j] = (1.0f - fr) * valid; s_wy1[j] = fr * valid;
    }
    __syncthreads();

    const int wv = t >> 6, lane = t & 63;
    const int jx = lane & 15, grp = lane >> 4;
    const int xj = min(jx, 13);
    const int x0 = s_ix0[xj], x1 = s_ix1[xj];
    const float wx0 = s_wx0[xj], wx1 = s_wx1[xj];
    const bool xact = (jx < 14);

    const size_t hw = (size_t)H * Wd;
    const float* fmb = fm + (size_t)b * C_CH * hw;

    for (int ci = 0; ci < 64; ++ci) {
        const int c = wv * 64 + ci;
        const float* fb = fmb + (size_t)c * hw;
        #pragma unroll
        for (int ky = 0; ky < 4; ++ky) {
            const int jy = ky * 4 + grp;
            const int yj = min(jy, 13);
            const int y0 = s_iy0[yj], y1 = s_iy1[yj];
            const float a0 = s_wy0[yj], a1 = s_wy1[yj];
            const float* r0 = fb + (size_t)y0 * Wd;
            const float* r1 = fb + (size_t)y1 * Wd;
            float v = a0 * (wx0 * r0[x0] + wx1 * r0[x1])
                    + a1 * (wx0 * r1[x0] + wx1 * r1[x1]);
            if (!xact || jy >= 14) v = 0.0f;
            v += __shfl_down(v, 1);    // combine jx pair
            v += __shfl_down(v, 16);   // combine jy pair (grp pair)
            if (((grp & 1) == 0) && ((jx & 1) == 0) && jx < 14) {
                const int by = ky * 2 + (grp >> 1);
                if (by < 7) {
                    const int bx = jx >> 1;
                    const float r = v * 0.25f;
                    const size_t d = (size_t)roi * DFEAT + c * 49 + by * 7 + bx;
                    const unsigned short hh = f2bf(r);
                    ph[d] = hh;
                    pl[d] = f2bf(r - bf2f(hh));
                }
            }
        }
    }
}

// ------------------------- fp32 -> bf16 hi/lo split -------------------------
__global__ __launch_bounds__(256) void split_fp32_bf16(
    const float* __restrict__ w, unsigned short* __restrict__ h,
    unsigned short* __restrict__ l, int n4)
{
    int i = blockIdx.x * 256 + threadIdx.x;
    const int stride = gridDim.x * 256;
    for (; i < n4; i += stride) {
        const float4 v = *(const float4*)(w + (size_t)i * 4);
        ushort4 hh, ll;
        hh.x = f2bf(v.x); ll.x = f2bf(v.x - bf2f(hh.x));
        hh.y = f2bf(v.y); ll.y = f2bf(v.y - bf2f(hh.y));
        hh.z = f2bf(v.z); ll.z = f2bf(v.z - bf2f(hh.z));
        hh.w = f2bf(v.w); ll.w = f2bf(v.w - bf2f(hh.w));
        *(ushort4*)(h + (size_t)i * 4) = hh;
        *(ushort4*)(l + (size_t)i * 4) = ll;
    }
}

// --------------------------- bf16x3 MFMA GEMM ------------------------------
// part[z][m][n] (no bias) = sum over k-slice of (Ah+Al)(Wh+Wl)^T, dropping Al*Wl.
// M = N = 1024 fixed. 128x128 tile, BK=32, 256 thr = 4 waves, each wave 64x64
// (4x4 frags of 16x16x32). global_load_lds 16B staging, ds_read_b128 frags.
#define GBM 128
#define GBN 128
#define GBK 32

__global__ __launch_bounds__(256) void gemm_bf16x3(
    const unsigned short* __restrict__ Ah, const unsigned short* __restrict__ Al,
    const unsigned short* __restrict__ Bh, const unsigned short* __restrict__ Bl,
    float* __restrict__ part, int K, int ksplit)
{
    __shared__ __align__(16) unsigned short sAh[GBM * GBK];
    __shared__ __align__(16) unsigned short sAl[GBM * GBK];
    __shared__ __align__(16) unsigned short sBh[GBN * GBK];
    __shared__ __align__(16) unsigned short sBl[GBN * GBK];

    const int t  = threadIdx.x;
    const int bm = blockIdx.y * GBM, bn = blockIdx.x * GBN;
    const int k0 = blockIdx.z * ksplit, k1 = k0 + ksplit;
    const int lane = t & 63, wv = t >> 6;
    const int wr = wv >> 1, wc = wv & 1;
    const int lm = lane & 15, quad = lane >> 4;

    f32x4 acc[4][4] = {};

    const int srow = t >> 2;        // staging row 0..63 (+q*64)
    const int skc  = (t & 3) * 8;   // staging k offset (elements)

    for (int kk = k0; kk < k1; kk += GBK) {
        #pragma unroll
        for (int q = 0; q < 2; ++q) {
            const int row = q * 64 + srow;
            const size_t ga = (size_t)(bm + row) * K + kk + skc;
            const size_t gb = (size_t)(bn + row) * K + kk + skc;
            const int lo = q * 4096 + t * 16;   // LDS byte offset
            g2lds16(Ah + ga, (char*)sAh + lo);
            g2lds16(Al + ga, (char*)sAl + lo);
            g2lds16(Bh + gb, (char*)sBh + lo);
            g2lds16(Bl + gb, (char*)sBl + lo);
        }
        __syncthreads();

        bf16x8 fah[4], fal[4], fbh[4], fbl[4];
        #pragma unroll
        for (int i = 0; i < 4; ++i) {
            fah[i] = *(const bf16x8*)&sAh[(wr * 64 + i * 16 + lm) * GBK + quad * 8];
            fal[i] = *(const bf16x8*)&sAl[(wr * 64 + i * 16 + lm) * GBK + quad * 8];
            fbh[i] = *(const bf16x8*)&sBh[(wc * 64 + i * 16 + lm) * GBK + quad * 8];
            fbl[i] = *(const bf16x8*)&sBl[(wc * 64 + i * 16 + lm) * GBK + quad * 8];
        }
        #pragma unroll
        for (int i = 0; i < 4; ++i)
            #pragma unroll
            for (int j = 0; j < 4; ++j)
                acc[i][j] = __builtin_amdgcn_mfma_f32_16x16x32_bf16(fah[i], fbh[j], acc[i][j], 0, 0, 0);
        #pragma unroll
        for (int i = 0; i < 4; ++i)
            #pragma unroll
            for (int j = 0; j < 4; ++j)
                acc[i][j] = __builtin_amdgcn_mfma_f32_16x16x32_bf16(fah[i], fbl[j], acc[i][j], 0, 0, 0);
        #pragma unroll
        for (int i = 0; i < 4; ++i)
            #pragma unroll
            for (int j = 0; j < 4; ++j)
                acc[i][j] = __builtin_amdgcn_mfma_f32_16x16x32_bf16(fal[i], fbh[j], acc[i][j], 0, 0, 0);
        __syncthreads();
    }

    float* out = part + (size_t)blockIdx.z * (HID * NROIS);
    #pragma unroll
    for (int i = 0; i < 4; ++i) {
        const int mbase = bm + wr * 64 + i * 16 + quad * 4;
        #pragma unroll
        for (int j = 0; j < 4; ++j) {
            const int n = bn + wc * 64 + j * 16 + lm;
            #pragma unroll
            for (int r = 0; r < 4; ++r)
                out[(size_t)(mbase + r) * HID + n] = acc[i][j][r];
        }
    }
}

// -------- split-K reduce + bias + relu (+ optional hi/lo split out) --------
// mode 0: write fp32 to ofp.  mode 1: write bf16 hi/lo to oh/ol.
__global__ __launch_bounds__(256) void reduce_bias_relu(
    const float* __restrict__ part, const float* __restrict__ bias,
    int S, int mode, unsigned short* __restrict__ oh,
    unsigned short* __restrict__ ol, float* __restrict__ ofp)
{
    const int i4 = blockIdx.x * 256 + threadIdx.x;   // over (1024*1024)/4
    const size_t off = (size_t)i4 * 4;
    const int n = (int)(off & (HID - 1));
    float4 s = *(const float4*)(part + off);
    for (int z = 1; z < S; ++z) {
        const float4 p = *(const float4*)(part + (size_t)z * HID * NROIS + off);
        s.x += p.x; s.y += p.y; s.z += p.z; s.w += p.w;
    }
    const float4 b = *(const float4*)(bias + n);
    s.x = fmaxf(s.x + b.x, 0.0f);
    s.y = fmaxf(s.y + b.y, 0.0f);
    s.z = fmaxf(s.z + b.z, 0.0f);
    s.w = fmaxf(s.w + b.w, 0.0f);
    if (mode == 0) {
        *(float4*)(ofp + off) = s;
    } else {
        ushort4 hh, ll;
        hh.x = f2bf(s.x); ll.x = f2bf(s.x - bf2f(hh.x));
        hh.y = f2bf(s.y); ll.y = f2bf(s.y - bf2f(hh.y));
        hh.z = f2bf(s.z); ll.z = f2bf(s.z - bf2f(hh.z));
        hh.w = f2bf(s.w); ll.w = f2bf(s.w - bf2f(hh.w));
        *(ushort4*)(oh + off) = hh;
        *(ushort4*)(ol + off) = ll;
    }
}

// ------------------------------ PREDICTOR ----------------------------------
__global__ __launch_bounds__(256) void pred_kernel(
    const float* __restrict__ A, const float* __restrict__ Wm,
    const float* __restrict__ bias, float* __restrict__ out)
{
    const int i = blockIdx.x;
    const int t = threadIdx.x;
    const int j = t & 31;
    const int s = t >> 5;

    __shared__ float red[8][32];

    float acc = 0.0f;
    if (j < NCLS) {
        const float4* a4 = (const float4*)(A  + (size_t)i * HID + s * 128);
        const float4* w4 = (const float4*)(Wm + (size_t)j * HID + s * 128);
        #pragma unroll 8
        for (int q = 0; q < 32; ++q) {
            const float4 a = a4[q], w = w4[q];
            acc += a.x * w.x + a.y * w.y + a.z * w.z + a.w * w.w;
        }
    }
    red[s][j] = acc;
    __syncthreads();
    if (s == 0 && j < NCLS) {
        float v = bias[j];
        #pragma unroll
        for (int q = 0; q < 8; ++q) v += red[q][j];
        out[(size_t)i * NCLS + j] = v;
    }
}

// ------------------------------- LAUNCH ------------------------------------
extern "C" void kernel_launch(void* const* d_in, const int* in_sizes, int n_in,
                              void* d_out, int out_size, void* d_ws, size_t ws_size,
                              hipStream_t stream) {
    (void)in_sizes; (void)n_in; (void)out_size;

    const float* fm0   = (const float*)d_in[0];
    const float* fm1   = (const float*)d_in[1];
    const float* fm2   = (const float*)d_in[2];
    const float* fm3   = (const float*)d_in[3];
    const float* rois  = (const float*)d_in[4];
    const float* fc1_w = (const float*)d_in[5];
    const float* fc1_b = (const float*)d_in[6];
    const float* fc2_w = (const float*)d_in[7];
    const float* fc2_b = (const float*)d_in[8];
    const float* p_w   = (const float*)d_in[9];
    const float* p_b   = (const float*)d_in[10];

    // ---- workspace layout ----
    const size_t SZ_POOL = (size_t)NROIS * DFEAT * 2;   // 25.7 MB (bf16)
    const size_t SZ_W1   = (size_t)HID * DFEAT * 2;     // 25.7 MB
    const size_t SZ_W2   = (size_t)HID * HID * 2;       // 2.1 MB
    const size_t SZ_FC1  = (size_t)NROIS * HID * 2;     // 2.1 MB
    const size_t SZ_FC2O = (size_t)NROIS * HID * 4;     // 4.2 MB
    const size_t SZ_PART1 = (size_t)HID * NROIS * 4;    // 4.2 MB per split

    const size_t fixed = 2 * SZ_POOL + 2 * SZ_W1 + 2 * SZ_W2 + 2 * SZ_FC1 + SZ_FC2O;
    int S1 = 8;
    while (S1 > 1 && fixed + (size_t)S1 * SZ_PART1 > ws_size) S1 >>= 1;
    const int S2 = (S1 < 4) ? S1 : 4;

    char* p = (char*)d_ws;
    unsigned short* ph   = (unsigned short*)p; p += SZ_POOL;
    unsigned short* pl   = (unsigned short*)p; p += SZ_POOL;
    unsigned short* w1h  = (unsigned short*)p; p += SZ_W1;
    unsigned short* w1l  = (unsigned short*)p; p += SZ_W1;
    unsigned short* w2h  = (unsigned short*)p; p += SZ_W2;
    unsigned short* w2l  = (unsigned short*)p; p += SZ_W2;
    unsigned short* fc1h = (unsigned short*)p; p += SZ_FC1;
    unsigned short* fc1l = (unsigned short*)p; p += SZ_FC1;
    float* fc2o = (float*)p; p += SZ_FC2O;
    float* part = (float*)p;

    float* outp = (float*)d_out;

    // 1. weight splits
    split_fp32_bf16<<<4096, 256, 0, stream>>>(fc1_w, w1h, w1l, HID * DFEAT / 4);
    split_fp32_bf16<<<1024, 256, 0, stream>>>(fc2_w, w2h, w2l, HID * HID / 4);

    // 2. roi align -> pooled hi/lo
    roi_pool_split<<<NROIS, 256, 0, stream>>>(fm0, fm1, fm2, fm3, rois, ph, pl);

    // 3. fc1: [1024,12544] x [1024,12544]^T, split-K S1
    {
        dim3 grid(HID / GBN, NROIS / GBM, S1);
        gemm_bf16x3<<<grid, 256, 0, stream>>>(ph, pl, w1h, w1l, part, DFEAT, DFEAT / S1);
    }
    reduce_bias_relu<<<NROIS * HID / 4 / 256, 256, 0, stream>>>(
        part, fc1_b, S1, 1, fc1h, fc1l, (float*)nullptr);

    // 4. fc2: [1024,1024] x [1024,1024]^T, split-K S2
    {
        dim3 grid(HID / GBN, NROIS / GBM, S2);
        gemm_bf16x3<<<grid, 256, 0, stream>>>(fc1h, fc1l, w2h, w2l, part, HID, HID / S2);
    }
    reduce_bias_relu<<<NROIS * HID / 4 / 256, 256, 0, stream>>>(
        part, fc2_b, S2, 0, (unsigned short*)nullptr, (unsigned short*)nullptr, fc2o);

    // 5. predictor
    pred_kernel<<<NROIS, 256, 0, stream>>>(fc2o, p_w, p_b, outp);
}